// Round 2
// baseline (1630.635 us; speedup 1.0000x reference)
//
#include <hip/hip_runtime.h>
#include <stdint.h>
#include <stddef.h>

typedef __attribute__((ext_vector_type(8))) short bf16x8;
typedef __attribute__((ext_vector_type(4))) float f32x4;
typedef unsigned short u16;
typedef unsigned int u32;

static constexpr int S_ = 2048, B_ = 2, H_ = 2048, NH_ = 16, D_ = 128, M_ = 2048, FF_ = 8192;
static constexpr int SB_ = S_ * B_;   // 4096 rows of x
static constexpr int MB_ = M_ * B_;   // 4096 rows of mem

__device__ __forceinline__ float b2f(u16 b) {
  union { u32 u; float f; } v; v.u = ((u32)b) << 16; return v.f;
}
__device__ __forceinline__ u16 f2b(float f) {
  union { float f; u32 u; } v; v.f = f;
  u32 u = v.u;
  return (u16)((u + 0x7FFFu + ((u >> 16) & 1u)) >> 16);
}
__device__ __forceinline__ float geluf(float x) {
  float x3 = x * x * x;
  return 0.5f * x * (1.0f + tanhf(0.7978845608028654f * (x + 0.044715f * x3)));
}

#define LDSP(p) (reinterpret_cast<__attribute__((address_space(3))) uint32_t*>(reinterpret_cast<uintptr_t>(p)))
#define GLBP(p) (reinterpret_cast<const __attribute__((address_space(1))) uint32_t*>(reinterpret_cast<uintptr_t>(p)))

// ---------------------------------------------------------------- detectors
// flags[0]: 1 = inputs are f32, 0 = inputs are bf16
// flags[1]: mask kind: 0=uint8 bool, 1=int32, 2=bf16, 3=f32
__global__ void detect_kinds(const u32* __restrict__ x0, const u32* __restrict__ mask, int* __restrict__ flags) {
  if (threadIdx.x == 0 && blockIdx.x == 0) {
    int cnt = 0;
    for (int i = 0; i < 256; ++i) {
      u32 e = (x0[i] >> 7) & 0xFFu;   // exponent field if low halfword is a bf16
      if (e >= 118u && e <= 130u) ++cnt;
    }
    flags[0] = (cnt >= 128) ? 0 : 1;
    int all01 = 1, allf = 1, allb = 1;
    for (int i = 0; i < 256; ++i) {
      u32 v = mask[i];
      if (v > 1u) all01 = 0;
      if (v != 0u && v != 0x3F800000u) allf = 0;
      u32 lo = v & 0xFFFFu, hi = v >> 16;
      if ((lo != 0u && lo != 0x3F80u) || (hi != 0u && hi != 0x3F80u)) allb = 0;
    }
    flags[1] = all01 ? 1 : (allf ? 3 : (allb ? 2 : 0));
  }
}

// masked -> 0, unmasked -> bf16(1.0)
__global__ void mask_cvt(const void* __restrict__ mraw, const int* __restrict__ flags, u16* __restrict__ mm) {
  int i = blockIdx.x * 256 + threadIdx.x;
  int kind = flags[1];
  int masked;
  if (kind == 1)      masked = ((const int*)mraw)[i] != 0;
  else if (kind == 3) masked = ((const float*)mraw)[i] != 0.0f;
  else if (kind == 2) masked = ((const u16*)mraw)[i] != 0;
  else                masked = ((const unsigned char*)mraw)[i] != 0;
  mm[i] = masked ? 0 : 0x3F80u;
}

__global__ void cvt_f32(const void* __restrict__ src, const int* __restrict__ flags, float* __restrict__ dst, int n) {
  int i = blockIdx.x * 256 + threadIdx.x;
  if (i < n) dst[i] = flags[0] ? ((const float*)src)[i] : b2f(((const u16*)src)[i]);
}

__global__ void cast_in_bf16(const void* __restrict__ src, const int* __restrict__ flags, u16* __restrict__ dst, int n8) {
  int i = blockIdx.x * 256 + threadIdx.x;
  if (i >= n8) return;
  if (flags[0]) {
    const float4* p = (const float4*)src;
    float4 a = p[i * 2], c = p[i * 2 + 1];
    bf16x8 o;
    o[0] = (short)f2b(a.x); o[1] = (short)f2b(a.y); o[2] = (short)f2b(a.z); o[3] = (short)f2b(a.w);
    o[4] = (short)f2b(c.x); o[5] = (short)f2b(c.y); o[6] = (short)f2b(c.z); o[7] = (short)f2b(c.w);
    *(bf16x8*)&dst[i * 8] = o;
  } else {
    *(bf16x8*)&dst[i * 8] = ((const bf16x8*)src)[i];
  }
}

// ------------------------------------------------------------ transpose+cast
// in [R][C] (f32 or bf16 per flag) -> out [C][R] bf16.  grid (C/64, R/64), 256 thr.
__global__ __launch_bounds__(256) void transpose_cast(const void* __restrict__ in, const int* __restrict__ flags,
                                                      u16* __restrict__ out, int R, int C) {
  __shared__ u16 tile[64][65];
  const int isf = flags[0];
  const int tr = blockIdx.y * 64, tc = blockIdx.x * 64;
  const int tx = threadIdx.x & 63, ty = threadIdx.x >> 6;
  const float* inf = (const float*)in;
  const u16* inb = (const u16*)in;
#pragma unroll
  for (int i = 0; i < 16; ++i) {
    int r = ty * 16 + i;
    size_t idx = (size_t)(tr + r) * C + tc + tx;
    tile[r][tx] = isf ? f2b(inf[idx]) : inb[idx];
  }
  __syncthreads();
#pragma unroll
  for (int i = 0; i < 16; ++i) {
    int c = ty * 16 + i;
    out[(size_t)(tc + c) * R + tr + tx] = tile[tx][c];
  }
}

// ---------------------------------------------------------------- layernorm
template <int EXT>
__global__ __launch_bounds__(256) void layernorm_k(const void* __restrict__ xin, const int* __restrict__ flags,
                                                   const float* __restrict__ g, const float* __restrict__ bta,
                                                   u16* __restrict__ out) {
  const int row = blockIdx.x, t = threadIdx.x;
  float v[8];
  bool bfmode = EXT && (flags[0] == 0);
  if (bfmode) {
    const u16* xr = (const u16*)xin + (size_t)row * H_ + t * 8;
    bf16x8 a = *(const bf16x8*)xr;
#pragma unroll
    for (int j = 0; j < 8; ++j) v[j] = b2f((u16)a[j]);
  } else {
    const float* xr = (const float*)xin + (size_t)row * H_ + t * 8;
    float4 a = *(const float4*)xr, c = *(const float4*)(xr + 4);
    v[0] = a.x; v[1] = a.y; v[2] = a.z; v[3] = a.w;
    v[4] = c.x; v[5] = c.y; v[6] = c.z; v[7] = c.w;
  }
  float s1 = 0.f, s2 = 0.f;
#pragma unroll
  for (int j = 0; j < 8; ++j) { s1 += v[j]; s2 += v[j] * v[j]; }
#pragma unroll
  for (int off = 32; off > 0; off >>= 1) { s1 += __shfl_down(s1, off); s2 += __shfl_down(s2, off); }
  __shared__ float red[8];
  const int w = t >> 6;
  if ((t & 63) == 0) { red[w] = s1; red[4 + w] = s2; }
  __syncthreads();
  s1 = red[0] + red[1] + red[2] + red[3];
  s2 = red[4] + red[5] + red[6] + red[7];
  const float mean = s1 * (1.0f / H_);
  const float rstd = rsqrtf(s2 * (1.0f / H_) - mean * mean + 1e-5f);
  bf16x8 o;
#pragma unroll
  for (int j = 0; j < 8; ++j) {
    float y = (v[j] - mean) * rstd * g[t * 8 + j] + bta[t * 8 + j];
    o[j] = (short)f2b(y);
  }
  *(bf16x8*)(out + (size_t)row * H_ + t * 8) = o;
}

// ------------------------------------------------------------------- GEMM
// 256x256 tile, 8-phase schedule (T2 st_16x32 swizzle + T3/T4 counted vmcnt + T5 setprio).
// C[Mr,N] = A[Mr,K] * Bt[N,K]^T.  512 threads = 8 waves (2M x 4N), per-wave 128x64 out.
// LDS: per operand a 4-slot ring of K-slice halves [256 rows][32 cols] bf16 (16KB each).
template <int GELU, int RES, int WF, int WB, int ODYN>
__global__ __launch_bounds__(512, 2) void gemm256(const u16* __restrict__ A, const u16* __restrict__ Bt,
                                                  const float* __restrict__ bias, const float* __restrict__ res,
                                                  void* __restrict__ outF, u16* __restrict__ outB,
                                                  const int* __restrict__ flags, int Mr, int N, int K) {
  __shared__ u16 ldsAB[65536];   // 128 KiB: A slots [0,32768), B slots [32768,65536)
  const int t = threadIdx.x;
  const int w = t >> 6, l = t & 63, lr = l & 15, lk = l >> 4;
  // T1: bijective XCD swizzle (m204)
  const int nwg = gridDim.x * gridDim.y;
  const int orig = blockIdx.y * gridDim.x + blockIdx.x;
  const int q = nwg >> 3, r = nwg & 7, xcd = orig & 7, lo = orig >> 3;
  const int wg = (xcd < r ? xcd * (q + 1) : r * (q + 1) + (xcd - r) * q) + lo;
  const int tn = (wg % gridDim.x) * 256;
  const int tm = (wg / gridDim.x) * 256;
  const int wr = w >> 2, wc = w & 3;

  // staging source (rule #21: linear LDS dest + inverse-swizzled global source)
  const int qb = t * 16;
  const int pb = qb ^ (((qb >> 9) & 1) << 5);
  const int srow = pb >> 6, scol = (pb & 63) >> 1;
  const size_t a0 = (size_t)(tm + srow) * K + scol;
  const size_t a1 = a0 + (size_t)128 * K;
  const size_t b0 = (size_t)(tn + srow) * K + scol;
  const size_t b1 = b0 + (size_t)128 * K;
  const int ldsw = w * 512;   // u16 offset of this wave's 1KB chunk within an 8KB issue-half

  // swizzled ds_read fragment offsets (u16 units), constant across slices
  int aoff[8], boff[4];
#pragma unroll
  for (int m = 0; m < 8; ++m) {
    int row = wr * 128 + m * 16 + lr;
    int by = row * 64 + lk * 16;
    by ^= ((by >> 9) & 1) << 5;
    aoff[m] = by >> 1;
  }
#pragma unroll
  for (int n = 0; n < 4; ++n) {
    int row = wc * 64 + n * 16 + lr;
    int by = row * 64 + lk * 16;
    by ^= ((by >> 9) & 1) << 5;
    boff[n] = by >> 1;
  }

  const int NS = K >> 5;   // K-slices of 32
  f32x4 acc[8][4] = {};

#define ASLOT(i) ((i) * 8192)
#define BSLOT(i) (32768 + (i) * 8192)
#define STG(baseptr, s0, s1, slotu, kofs) do {                                                            \
    __builtin_amdgcn_global_load_lds(GLBP((baseptr) + (s0) + (kofs)), LDSP(ldsAB + (slotu) + ldsw), 16, 0, 0); \
    __builtin_amdgcn_global_load_lds(GLBP((baseptr) + (s1) + (kofs)), LDSP(ldsAB + (slotu) + 4096 + ldsw), 16, 0, 0); \
  } while (0)

  // prologue: A0,B0,A1,B1 -> vmcnt(4) -> A2,B2,A3 -> vmcnt(6) -> barrier
  STG(A, a0, a1, ASLOT(0), 0);
  STG(Bt, b0, b1, BSLOT(0), 0);
  if (1 < NS) { STG(A, a0, a1, ASLOT(1), 32); STG(Bt, b0, b1, BSLOT(1), 32); }
  asm volatile("s_waitcnt vmcnt(4)" ::: "memory");
  if (2 < NS) { STG(A, a0, a1, ASLOT(2), 64); STG(Bt, b0, b1, BSLOT(2), 64); }
  if (3 < NS) STG(A, a0, a1, ASLOT(3), 96);
  asm volatile("s_waitcnt vmcnt(6)" ::: "memory");
  __builtin_amdgcn_s_barrier();

  for (int s = 0; s < NS; ++s) {
    const int sa = s & 3;
    const u16* As = ldsAB + ASLOT(sa);
    const u16* Bs = ldsAB + BSLOT(sa);
    // ---- phase 1: read A frags (held across both phases) + B n0,n1; stage B_{s+3}
    bf16x8 af[8], bq0, bq1;
#pragma unroll
    for (int m = 0; m < 8; ++m) af[m] = *(const bf16x8*)(As + aoff[m]);
    bq0 = *(const bf16x8*)(Bs + boff[0]);
    bq1 = *(const bf16x8*)(Bs + boff[1]);
    { const int sb = s + 3; if (sb < NS) STG(Bt, b0, b1, BSLOT(sb & 3), sb * 32); }
    __builtin_amdgcn_s_barrier();
    asm volatile("s_waitcnt lgkmcnt(0)" ::: "memory");
    __builtin_amdgcn_sched_barrier(0);
    __builtin_amdgcn_s_setprio(1);
#pragma unroll
    for (int m = 0; m < 8; ++m) {
      acc[m][0] = __builtin_amdgcn_mfma_f32_16x16x32_bf16(af[m], bq0, acc[m][0], 0, 0, 0);
      acc[m][1] = __builtin_amdgcn_mfma_f32_16x16x32_bf16(af[m], bq1, acc[m][1], 0, 0, 0);
    }
    __builtin_amdgcn_s_setprio(0);
    __builtin_amdgcn_s_barrier();
    // ---- phase 2: read B n2,n3; stage A_{s+4}
    bf16x8 bq2 = *(const bf16x8*)(Bs + boff[2]);
    bf16x8 bq3 = *(const bf16x8*)(Bs + boff[3]);
    { const int sa4 = s + 4; if (sa4 < NS) STG(A, a0, a1, ASLOT(sa4 & 3), sa4 * 32); }
    __builtin_amdgcn_s_barrier();
    asm volatile("s_waitcnt lgkmcnt(0)" ::: "memory");
    __builtin_amdgcn_sched_barrier(0);
    __builtin_amdgcn_s_setprio(1);
#pragma unroll
    for (int m = 0; m < 8; ++m) {
      acc[m][2] = __builtin_amdgcn_mfma_f32_16x16x32_bf16(af[m], bq2, acc[m][2], 0, 0, 0);
      acc[m][3] = __builtin_amdgcn_mfma_f32_16x16x32_bf16(af[m], bq3, acc[m][3], 0, 0, 0);
    }
    __builtin_amdgcn_s_setprio(0);
    // counted vmcnt: steady state only at odd slices; exact drain in tail
    const int rem = NS - 1 - s;
    if (rem > 3) {
      if (s & 1) asm volatile("s_waitcnt vmcnt(6)" ::: "memory");
    } else if (rem == 3) {
      asm volatile("s_waitcnt vmcnt(8)" ::: "memory");
    } else if (rem == 2) {
      asm volatile("s_waitcnt vmcnt(4)" ::: "memory");
    } else if (rem == 1) {
      asm volatile("s_waitcnt vmcnt(0)" ::: "memory");
    }
    __builtin_amdgcn_s_barrier();
  }
#undef STG
#undef ASLOT
#undef BSLOT

  const int obf = ODYN ? (flags[0] ? 0 : 1) : 0;
#pragma unroll
  for (int m = 0; m < 8; ++m) {
#pragma unroll
    for (int n = 0; n < 4; ++n) {
      const int col = tn + wc * 64 + n * 16 + lr;
      const float bv = bias[col];
#pragma unroll
      for (int j = 0; j < 4; ++j) {
        const int rw = tm + wr * 128 + m * 16 + lk * 4 + j;
        float vv = acc[m][n][j] + bv;
        if (RES) vv += res[(size_t)rw * N + col];
        if (GELU) vv = geluf(vv);
        if (WF) {
          if (ODYN && obf) ((u16*)outF)[(size_t)rw * N + col] = f2b(vv);
          else ((float*)outF)[(size_t)rw * N + col] = vv;
        }
        if (WB) outB[(size_t)rw * N + col] = f2b(vv);
      }
    }
  }
}

// --------------------------------------------------------------- l2 norms
__global__ __launch_bounds__(256) void l2_q(const float* __restrict__ qpre, u16* __restrict__ Q) {
  const int t = threadIdx.x;
  const int g = blockIdx.x * 64 + (t >> 2);
  const int lg = t & 3;
  const int h = g & (NH_ - 1), sb = g >> 4;
  const float* p = qpre + (size_t)sb * H_ + h * D_ + lg * 32;
  float vv[32];
  float ss = 0.f;
#pragma unroll
  for (int i = 0; i < 8; ++i) {
    float4 a = *(const float4*)&p[i * 4];
    vv[i * 4 + 0] = a.x; vv[i * 4 + 1] = a.y; vv[i * 4 + 2] = a.z; vv[i * 4 + 3] = a.w;
    ss += a.x * a.x + a.y * a.y + a.z * a.z + a.w * a.w;
  }
  ss += __shfl_xor(ss, 1); ss += __shfl_xor(ss, 2);
  const float sc = rsqrtf(ss + 1e-12f);
  const int s = sb >> 1, b = sb & 1;
  u16* o = Q + ((size_t)(b * NH_ + h) * S_ + s) * D_ + lg * 32;
#pragma unroll
  for (int i = 0; i < 4; ++i) {
    bf16x8 ov;
#pragma unroll
    for (int j = 0; j < 8; ++j) ov[j] = (short)f2b(vv[i * 8 + j] * sc);
    *(bf16x8*)&o[i * 8] = ov;
  }
}

__global__ __launch_bounds__(256) void l2_kv(const float* __restrict__ kvpre, u16* __restrict__ Kq, u16* __restrict__ Vt) {
  __shared__ u16 vtT[128][72];
  const int t = threadIdx.x;
  const int bid = blockIdx.x;
  const int mt = bid & 31, h = (bid >> 5) & 15, b = bid >> 9;
  const int lm = t >> 2, lg = t & 3;
  const int m = mt * 64 + lm;
  const size_t rowoff = (size_t)(m * B_ + b) * (2 * H_) + h * 256;
  float vv[32];
  { // K half
    const float* p = kvpre + rowoff + lg * 32;
    float ss = 0.f;
#pragma unroll
    for (int i = 0; i < 8; ++i) {
      float4 a = *(const float4*)&p[i * 4];
      vv[i * 4 + 0] = a.x; vv[i * 4 + 1] = a.y; vv[i * 4 + 2] = a.z; vv[i * 4 + 3] = a.w;
      ss += a.x * a.x + a.y * a.y + a.z * a.z + a.w * a.w;
    }
    ss += __shfl_xor(ss, 1); ss += __shfl_xor(ss, 2);
    const float sc = rsqrtf(ss + 1e-12f);
    u16* o = Kq + ((size_t)(b * NH_ + h) * M_ + m) * D_ + lg * 32;
#pragma unroll
    for (int i = 0; i < 4; ++i) {
      bf16x8 ov;
#pragma unroll
      for (int j = 0; j < 8; ++j) ov[j] = (short)f2b(vv[i * 8 + j] * sc);
      *(bf16x8*)&o[i * 8] = ov;
    }
  }
  { // V half -> LDS transposed
    const float* p = kvpre + rowoff + 128 + lg * 32;
    float ss = 0.f;
#pragma unroll
    for (int i = 0; i < 8; ++i) {
      float4 a = *(const float4*)&p[i * 4];
      vv[i * 4 + 0] = a.x; vv[i * 4 + 1] = a.y; vv[i * 4 + 2] = a.z; vv[i * 4 + 3] = a.w;
      ss += a.x * a.x + a.y * a.y + a.z * a.z + a.w * a.w;
    }
    ss += __shfl_xor(ss, 1); ss += __shfl_xor(ss, 2);
    const float sc = rsqrtf(ss + 1e-12f);
#pragma unroll
    for (int i = 0; i < 32; ++i) vtT[lg * 32 + i][lm] = f2b(vv[i] * sc);
  }
  __syncthreads();
  const int d = t >> 1, half = t & 1;
  u16* o = Vt + ((size_t)(b * NH_ + h) * D_ + d) * M_ + mt * 64 + half * 32;
#pragma unroll
  for (int i = 0; i < 4; ++i) {
    bf16x8 ov = *(const bf16x8*)&vtT[d][half * 32 + i * 8];
    *(bf16x8*)&o[i * 8] = ov;
  }
}

// -------------------------------------------------------------- attention
__global__ __launch_bounds__(256) void attn_k(const u16* __restrict__ Q, const u16* __restrict__ Kq,
                                              const u16* __restrict__ Vt, const u16* __restrict__ MM,
                                              u16* __restrict__ ctx) {
  __shared__ u16 Kl[64 * 128];     // [m][d], source-swizzled
  __shared__ u16 Vl[128 * 64];     // [d][m], source-swizzled
  __shared__ u16 Pl[4][32 * 72];   // per-wave P, padded
  const int t = threadIdx.x, w = t >> 6, l = t & 63, lr = l & 15, lk = l >> 4;
  const int st = blockIdx.x * 128;
  const int bh = blockIdx.y, b = bh >> 4, h = bh & 15;
  const u16* Qb = Q + ((size_t)bh * S_ + st + w * 32) * D_;
  bf16x8 qf[2][4];
#pragma unroll
  for (int sf = 0; sf < 2; ++sf)
#pragma unroll
    for (int kc = 0; kc < 4; ++kc)
      qf[sf][kc] = *(const bf16x8*)&Qb[(sf * 16 + lr) * D_ + kc * 32 + lk * 8];
  f32x4 oacc[2][8] = {};
  float den[2][4] = {};
  const u16* Kb = Kq + (size_t)bh * M_ * D_;
  const u16* Vb = Vt + (size_t)bh * D_ * M_;
  const u16* Mb = MM + (size_t)b * S_ * M_ + (size_t)(st + w * 32) * M_;
  const float invn = 0.08838834764831845f;  // 1/sqrt(128)

  for (int m0 = 0; m0 < M_; m0 += 64) {
#pragma unroll
    for (int i = 0; i < 4; ++i) {
      int j = i * 256 + w * 64 + l;
      int r = j >> 4, c = j & 15, cs = c ^ (r & 7);
      __builtin_amdgcn_global_load_lds(GLBP(Kb + (size_t)(m0 + r) * D_ + cs * 8),
                                       LDSP(&Kl[(i * 256 + w * 64) * 8]), 16, 0, 0);
    }
#pragma unroll
    for (int i = 0; i < 4; ++i) {
      int j = i * 256 + w * 64 + l;
      int r = j >> 3, c = j & 7, cs = c ^ (r & 7);
      __builtin_amdgcn_global_load_lds(GLBP(Vb + (size_t)r * M_ + m0 + cs * 8),
                                       LDSP(&Vl[(i * 256 + w * 64) * 8]), 16, 0, 0);
    }
    __syncthreads();
    f32x4 sc[2][4] = {};
#pragma unroll
    for (int mf = 0; mf < 4; ++mf) {
      int rowm = mf * 16 + lr;
#pragma unroll
      for (int kc = 0; kc < 4; ++kc) {
        int cc = (kc * 4 + lk) ^ (rowm & 7);
        bf16x8 kfv = *(const bf16x8*)&Kl[rowm * 128 + cc * 8];
#pragma unroll
        for (int sf = 0; sf < 2; ++sf)
          sc[sf][mf] = __builtin_amdgcn_mfma_f32_16x16x32_bf16(qf[sf][kc], kfv, sc[sf][mf], 0, 0, 0);
      }
    }
#pragma unroll
    for (int sf = 0; sf < 2; ++sf)
#pragma unroll
      for (int mf = 0; mf < 4; ++mf) {
        int mcol = m0 + mf * 16 + lr;
#pragma unroll
        for (int j2 = 0; j2 < 4; ++j2) {
          int rloc = sf * 16 + lk * 4 + j2;
          float p = __expf(sc[sf][mf][j2] * invn);
          u16 mv = Mb[(size_t)rloc * M_ + mcol];
          p = mv ? p : 0.0f;
          den[sf][j2] += p;
          Pl[w][rloc * 72 + mf * 16 + lr] = f2b(p);
        }
      }
    __syncthreads();
#pragma unroll
    for (int kc2 = 0; kc2 < 2; ++kc2) {
      bf16x8 pa[2];
#pragma unroll
      for (int sf = 0; sf < 2; ++sf)
        pa[sf] = *(const bf16x8*)&Pl[w][(sf * 16 + lr) * 72 + kc2 * 32 + lk * 8];
#pragma unroll
      for (int nf = 0; nf < 8; ++nf) {
        int dd = nf * 16 + lr;
        int cc = (kc2 * 4 + lk) ^ (dd & 7);
        bf16x8 vf = *(const bf16x8*)&Vl[dd * 64 + cc * 8];
#pragma unroll
        for (int sf = 0; sf < 2; ++sf)
          oacc[sf][nf] = __builtin_amdgcn_mfma_f32_16x16x32_bf16(pa[sf], vf, oacc[sf][nf], 0, 0, 0);
      }
    }
    __syncthreads();
  }
#pragma unroll
  for (int sf = 0; sf < 2; ++sf)
#pragma unroll
    for (int j2 = 0; j2 < 4; ++j2) {
      float d = den[sf][j2];
      d += __shfl_xor(d, 1); d += __shfl_xor(d, 2); d += __shfl_xor(d, 4); d += __shfl_xor(d, 8);
      den[sf][j2] = 1.0f / fmaxf(d, 1e-20f);
    }
#pragma unroll
  for (int sf = 0; sf < 2; ++sf)
#pragma unroll
    for (int nf = 0; nf < 8; ++nf)
#pragma unroll
      for (int j2 = 0; j2 < 4; ++j2) {
        int s = st + w * 32 + sf * 16 + lk * 4 + j2;
        int dd = nf * 16 + lr;
        ctx[((size_t)s * B_ + b) * H_ + h * D_ + dd] = f2b(oacc[sf][nf][j2] * den[sf][j2]);
      }
}

// ------------------------------------------------------------------- host
extern "C" void kernel_launch(void* const* d_in, const int* in_sizes, int n_in,
                              void* d_out, int out_size, void* d_ws, size_t ws_size,
                              hipStream_t stream) {
  (void)in_sizes; (void)n_in; (void)out_size; (void)ws_size;
  char* ws = (char*)d_ws;
  u16* WT     = (u16*)(ws + 0);            // 33.55 MB  transposed bf16 weights (reused)
  void* MID   = (void*)(ws + 33554432);    // 67.11 MB  mlp mid bf16 / q_pre f32 / kv_pre f32
  float* XF   = (float*)(ws + 100663296);  // 33.55 MB  running x (f32)
  u16* HB     = (u16*)(ws + 134217728);    // 16.78 MB  LN outputs bf16
  u16* MEMB   = (u16*)(ws + 150994944);    // 16.78 MB  mem bf16, later ctx bf16
  u16* QB     = (u16*)(ws + 167772160);    // 16.78 MB  Q [B][NH][S][D]
  u16* KB     = (u16*)(ws + 184549376);    // 16.78 MB  K [B][NH][M][D]
  u16* VTB    = (u16*)(ws + 201326592);    // 16.78 MB  V^T [B][NH][D][M]
  u16* MMUL   = (u16*)(ws + 218103808);    // 16.78 MB  multiplicative mask bf16
  float* SM   = (float*)(ws + 234881024);  // small f32 arrays
  int* FLAGS  = (int*)(ws + 235044864);

  float* Bias1  = SM + 0;      // b_mlp1_in  8192
  float* Bias1o = SM + 8192;   // b_mlp1_out 2048
  float* BiasQ  = SM + 10240;  // b_q        2048
  float* BiasKV = SM + 12288;  // b_kv       4096
  float* BiasD  = SM + 16384;  // b_dense    2048
  float* Bias2  = SM + 18432;  // b_mlp2_in  8192
  float* Bias2o = SM + 26624;  // b_mlp2_out 2048
  float* G1v = SM + 28672; float* B1v = SM + 30720;
  float* G2v = SM + 32768; float* B2v = SM + 34816;
  float* G3v = SM + 36864; float* B3v = SM + 38912;

  detect_kinds<<<1, 64, 0, stream>>>((const u32*)d_in[0], (const u32*)d_in[2], FLAGS);

  cvt_f32<<<32, 256, 0, stream>>>(d_in[10], FLAGS, Bias1, 8192);
  cvt_f32<<<8, 256, 0, stream>>>(d_in[12], FLAGS, Bias1o, 2048);
  cvt_f32<<<8, 256, 0, stream>>>(d_in[14], FLAGS, BiasQ, 2048);
  cvt_f32<<<16, 256, 0, stream>>>(d_in[16], FLAGS, BiasKV, 4096);
  cvt_f32<<<8, 256, 0, stream>>>(d_in[18], FLAGS, BiasD, 2048);
  cvt_f32<<<32, 256, 0, stream>>>(d_in[20], FLAGS, Bias2, 8192);
  cvt_f32<<<8, 256, 0, stream>>>(d_in[22], FLAGS, Bias2o, 2048);
  cvt_f32<<<8, 256, 0, stream>>>(d_in[3], FLAGS, G1v, 2048);
  cvt_f32<<<8, 256, 0, stream>>>(d_in[4], FLAGS, B1v, 2048);
  cvt_f32<<<8, 256, 0, stream>>>(d_in[5], FLAGS, G2v, 2048);
  cvt_f32<<<8, 256, 0, stream>>>(d_in[6], FLAGS, B2v, 2048);
  cvt_f32<<<8, 256, 0, stream>>>(d_in[7], FLAGS, G3v, 2048);
  cvt_f32<<<8, 256, 0, stream>>>(d_in[8], FLAGS, B3v, 2048);

  mask_cvt<<<(B_ * S_ * M_) / 256, 256, 0, stream>>>(d_in[2], FLAGS, MMUL);
  cast_in_bf16<<<(MB_ * H_ / 8) / 256, 256, 0, stream>>>(d_in[1], FLAGS, MEMB, MB_ * H_ / 8);

  dim3 blk(256);
  dim3 blk5(512);
  // ---- mlp1: x = mlp(ln1(x))  (no residual)
  layernorm_k<1><<<SB_, blk, 0, stream>>>(d_in[0], FLAGS, G1v, B1v, HB);
  transpose_cast<<<dim3(FF_ / 64, H_ / 64), blk, 0, stream>>>(d_in[9], FLAGS, WT, H_, FF_);
  gemm256<1, 0, 0, 1, 0><<<dim3(FF_ / 256, SB_ / 256), blk5, 0, stream>>>(HB, WT, Bias1, nullptr, nullptr, (u16*)MID, FLAGS, SB_, FF_, H_);
  transpose_cast<<<dim3(H_ / 64, FF_ / 64), blk, 0, stream>>>(d_in[11], FLAGS, WT, FF_, H_);
  gemm256<0, 0, 1, 0, 0><<<dim3(H_ / 256, SB_ / 256), blk5, 0, stream>>>((u16*)MID, WT, Bias1o, nullptr, XF, nullptr, FLAGS, SB_, H_, FF_);

  // ---- memory attention
  layernorm_k<0><<<SB_, blk, 0, stream>>>(XF, FLAGS, G2v, B2v, HB);
  transpose_cast<<<dim3(H_ / 64, H_ / 64), blk, 0, stream>>>(d_in[13], FLAGS, WT, H_, H_);
  gemm256<0, 0, 1, 0, 0><<<dim3(H_ / 256, SB_ / 256), blk5, 0, stream>>>(HB, WT, BiasQ, nullptr, MID, nullptr, FLAGS, SB_, H_, H_);
  l2_q<<<(SB_ * NH_) / 64, blk, 0, stream>>>((const float*)MID, QB);
  transpose_cast<<<dim3(2 * H_ / 64, H_ / 64), blk, 0, stream>>>(d_in[15], FLAGS, WT, H_, 2 * H_);
  gemm256<0, 0, 1, 0, 0><<<dim3(2 * H_ / 256, MB_ / 256), blk5, 0, stream>>>(MEMB, WT, BiasKV, nullptr, MID, nullptr, FLAGS, MB_, 2 * H_, H_);
  l2_kv<<<B_ * NH_ * (M_ / 64), blk, 0, stream>>>((const float*)MID, KB, VTB);
  attn_k<<<dim3(S_ / 128, B_ * NH_), blk, 0, stream>>>(QB, KB, VTB, MMUL, MEMB);
  transpose_cast<<<dim3(H_ / 64, H_ / 64), blk, 0, stream>>>(d_in[17], FLAGS, WT, H_, H_);
  gemm256<0, 1, 1, 0, 0><<<dim3(H_ / 256, SB_ / 256), blk5, 0, stream>>>(MEMB, WT, BiasD, XF, XF, nullptr, FLAGS, SB_, H_, H_);

  // ---- mlp2 with residual
  layernorm_k<0><<<SB_, blk, 0, stream>>>(XF, FLAGS, G3v, B3v, HB);
  transpose_cast<<<dim3(FF_ / 64, H_ / 64), blk, 0, stream>>>(d_in[19], FLAGS, WT, H_, FF_);
  gemm256<1, 0, 0, 1, 0><<<dim3(FF_ / 256, SB_ / 256), blk5, 0, stream>>>(HB, WT, Bias2, nullptr, nullptr, (u16*)MID, FLAGS, SB_, FF_, H_);
  transpose_cast<<<dim3(H_ / 64, FF_ / 64), blk, 0, stream>>>(d_in[21], FLAGS, WT, FF_, H_);
  gemm256<0, 1, 1, 0, 1><<<dim3(H_ / 256, SB_ / 256), blk5, 0, stream>>>((u16*)MID, WT, Bias2o, XF, d_out, nullptr, FLAGS, SB_, H_, FF_);
}

// Round 3
// 1382.444 us; speedup vs baseline: 1.1795x; 1.1795x over previous
//
#include <hip/hip_runtime.h>
#include <stdint.h>
#include <stddef.h>

typedef __attribute__((ext_vector_type(8))) short bf16x8;
typedef __attribute__((ext_vector_type(4))) float f32x4;
typedef unsigned short u16;
typedef unsigned int u32;

static constexpr int S_ = 2048, B_ = 2, H_ = 2048, NH_ = 16, D_ = 128, M_ = 2048, FF_ = 8192;
static constexpr int SB_ = S_ * B_;   // 4096 rows of x
static constexpr int MB_ = M_ * B_;   // 4096 rows of mem

__device__ __forceinline__ float b2f(u16 b) {
  union { u32 u; float f; } v; v.u = ((u32)b) << 16; return v.f;
}
__device__ __forceinline__ u16 f2b(float f) {
  union { float f; u32 u; } v; v.f = f;
  u32 u = v.u;
  return (u16)((u + 0x7FFFu + ((u >> 16) & 1u)) >> 16);
}
__device__ __forceinline__ float geluf(float x) {
  float x3 = x * x * x;
  return 0.5f * x * (1.0f + tanhf(0.7978845608028654f * (x + 0.044715f * x3)));
}

#define LDSP(p) (reinterpret_cast<__attribute__((address_space(3))) uint32_t*>(reinterpret_cast<uintptr_t>(p)))
#define GLBP(p) (reinterpret_cast<const __attribute__((address_space(1))) uint32_t*>(reinterpret_cast<uintptr_t>(p)))

// ---------------------------------------------------------------- detectors
// flags[0]: 1 = inputs are f32, 0 = inputs are bf16
// flags[1]: mask kind: 0=uint8 bool, 1=int32, 2=bf16, 3=f32
__global__ void detect_kinds(const u32* __restrict__ x0, const u32* __restrict__ mask, int* __restrict__ flags) {
  if (threadIdx.x == 0 && blockIdx.x == 0) {
    int cnt = 0;
    for (int i = 0; i < 256; ++i) {
      u32 e = (x0[i] >> 7) & 0xFFu;   // exponent field if low halfword is a bf16
      if (e >= 118u && e <= 130u) ++cnt;
    }
    flags[0] = (cnt >= 128) ? 0 : 1;
    int all01 = 1, allf = 1, allb = 1;
    for (int i = 0; i < 256; ++i) {
      u32 v = mask[i];
      if (v > 1u) all01 = 0;
      if (v != 0u && v != 0x3F800000u) allf = 0;
      u32 lo = v & 0xFFFFu, hi = v >> 16;
      if ((lo != 0u && lo != 0x3F80u) || (hi != 0u && hi != 0x3F80u)) allb = 0;
    }
    flags[1] = all01 ? 1 : (allf ? 3 : (allb ? 2 : 0));
  }
}

// masked -> 0, unmasked -> bf16(1.0)
__global__ void mask_cvt(const void* __restrict__ mraw, const int* __restrict__ flags, u16* __restrict__ mm) {
  int i = blockIdx.x * 256 + threadIdx.x;
  int kind = flags[1];
  int masked;
  if (kind == 1)      masked = ((const int*)mraw)[i] != 0;
  else if (kind == 3) masked = ((const float*)mraw)[i] != 0.0f;
  else if (kind == 2) masked = ((const u16*)mraw)[i] != 0;
  else                masked = ((const unsigned char*)mraw)[i] != 0;
  mm[i] = masked ? 0 : 0x3F80u;
}

__global__ void cvt_f32(const void* __restrict__ src, const int* __restrict__ flags, float* __restrict__ dst, int n) {
  int i = blockIdx.x * 256 + threadIdx.x;
  if (i < n) dst[i] = flags[0] ? ((const float*)src)[i] : b2f(((const u16*)src)[i]);
}

__global__ void cast_in_bf16(const void* __restrict__ src, const int* __restrict__ flags, u16* __restrict__ dst, int n8) {
  int i = blockIdx.x * 256 + threadIdx.x;
  if (i >= n8) return;
  if (flags[0]) {
    const float4* p = (const float4*)src;
    float4 a = p[i * 2], c = p[i * 2 + 1];
    bf16x8 o;
    o[0] = (short)f2b(a.x); o[1] = (short)f2b(a.y); o[2] = (short)f2b(a.z); o[3] = (short)f2b(a.w);
    o[4] = (short)f2b(c.x); o[5] = (short)f2b(c.y); o[6] = (short)f2b(c.z); o[7] = (short)f2b(c.w);
    *(bf16x8*)&dst[i * 8] = o;
  } else {
    *(bf16x8*)&dst[i * 8] = ((const bf16x8*)src)[i];
  }
}

// ------------------------------------------------------------ transpose+cast
// in [R][C] (f32 or bf16 per flag) -> out [C][R] bf16.  grid (C/64, R/64), 256 thr.
__global__ __launch_bounds__(256) void transpose_cast(const void* __restrict__ in, const int* __restrict__ flags,
                                                      u16* __restrict__ out, int R, int C) {
  __shared__ u16 tile[64][65];
  const int isf = flags[0];
  const int tr = blockIdx.y * 64, tc = blockIdx.x * 64;
  const int tx = threadIdx.x & 63, ty = threadIdx.x >> 6;
  const float* inf = (const float*)in;
  const u16* inb = (const u16*)in;
#pragma unroll
  for (int i = 0; i < 16; ++i) {
    int r = ty * 16 + i;
    size_t idx = (size_t)(tr + r) * C + tc + tx;
    tile[r][tx] = isf ? f2b(inf[idx]) : inb[idx];
  }
  __syncthreads();
#pragma unroll
  for (int i = 0; i < 16; ++i) {
    int c = ty * 16 + i;
    out[(size_t)(tc + c) * R + tr + tx] = tile[tx][c];
  }
}

// ---------------------------------------------------------------- layernorm
template <int EXT>
__global__ __launch_bounds__(256) void layernorm_k(const void* __restrict__ xin, const int* __restrict__ flags,
                                                   const float* __restrict__ g, const float* __restrict__ bta,
                                                   u16* __restrict__ out) {
  const int row = blockIdx.x, t = threadIdx.x;
  float v[8];
  bool bfmode = EXT && (flags[0] == 0);
  if (bfmode) {
    const u16* xr = (const u16*)xin + (size_t)row * H_ + t * 8;
    bf16x8 a = *(const bf16x8*)xr;
#pragma unroll
    for (int j = 0; j < 8; ++j) v[j] = b2f((u16)a[j]);
  } else {
    const float* xr = (const float*)xin + (size_t)row * H_ + t * 8;
    float4 a = *(const float4*)xr, c = *(const float4*)(xr + 4);
    v[0] = a.x; v[1] = a.y; v[2] = a.z; v[3] = a.w;
    v[4] = c.x; v[5] = c.y; v[6] = c.z; v[7] = c.w;
  }
  float s1 = 0.f, s2 = 0.f;
#pragma unroll
  for (int j = 0; j < 8; ++j) { s1 += v[j]; s2 += v[j] * v[j]; }
#pragma unroll
  for (int off = 32; off > 0; off >>= 1) { s1 += __shfl_down(s1, off); s2 += __shfl_down(s2, off); }
  __shared__ float red[8];
  const int w = t >> 6;
  if ((t & 63) == 0) { red[w] = s1; red[4 + w] = s2; }
  __syncthreads();
  s1 = red[0] + red[1] + red[2] + red[3];
  s2 = red[4] + red[5] + red[6] + red[7];
  const float mean = s1 * (1.0f / H_);
  const float rstd = rsqrtf(s2 * (1.0f / H_) - mean * mean + 1e-5f);
  bf16x8 o;
#pragma unroll
  for (int j = 0; j < 8; ++j) {
    float y = (v[j] - mean) * rstd * g[t * 8 + j] + bta[t * 8 + j];
    o[j] = (short)f2b(y);
  }
  *(bf16x8*)(out + (size_t)row * H_ + t * 8) = o;
}

// ------------------------------------------------------------------- GEMM
// 256xBN tile (BN=256 or 128), 2-phase-minimum schedule with 4-slot ring,
// counted vmcnt, ONE barrier per K-slice (BK=32).  512 threads = 8 waves.
// BN=256: waves 2Mx4N (128x64 out each); BN=128: waves 4Mx2N (64x64 each).
// T2 st_16x32 swizzle: linear global_load_lds dest + inverse-swizzled global
// source + swizzled ds_read (rule #21).  T1 bijective XCD swizzle (m204).
// Assumes NS = K/32 >= 4.
template <int BN, int GELU, int RES, int WF, int WB, int ODYN>
__global__ __launch_bounds__(512, 2) void gemm2ph(const u16* __restrict__ A, const u16* __restrict__ Bt,
                                                  const float* __restrict__ bias, const float* __restrict__ res,
                                                  void* __restrict__ outF, u16* __restrict__ outB,
                                                  const int* __restrict__ flags, int Mr, int N, int K) {
  constexpr int AF = (BN == 256) ? 8 : 4;   // A frags per wave
  constexpr int BSL = BN * 32;              // u16 per B slot
  __shared__ u16 ldsAB[32768 + 4 * BSL];    // A: 4 x 16KB, B: 4 x (BN*64B)
  const int t = threadIdx.x;
  const int w = t >> 6, l = t & 63, lr = l & 15, lk = l >> 4;
  // T1: bijective XCD swizzle (m204)
  const int nwg = gridDim.x * gridDim.y;
  const int orig = blockIdx.y * gridDim.x + blockIdx.x;
  const int q = nwg >> 3, r = nwg & 7, xcd = orig & 7, lo = orig >> 3;
  const int wg = (xcd < r ? xcd * (q + 1) : r * (q + 1) + (xcd - r) * q) + lo;
  const int tn = (wg % gridDim.x) * BN;
  const int tm = (wg / gridDim.x) * 256;
  const int wr = (BN == 256) ? (w >> 2) : (w >> 1);
  const int wc = (BN == 256) ? (w & 3) : (w & 1);

  // staging source (linear LDS dest + inverse-swizzled global source)
  const int qb = t * 16;
  const int pb = qb ^ (((qb >> 9) & 1) << 5);
  const int srow = pb >> 6, scol = (pb & 63) >> 1;
  const size_t a0 = (size_t)(tm + srow) * K + scol;
  const size_t a1 = a0 + (size_t)128 * K;
  const size_t b0 = (size_t)(tn + srow) * K + scol;
  const size_t b1 = b0 + (size_t)128 * K;   // only used when BN==256
  const int ldsw = w * 512;                  // u16: wave's 1KB chunk in an 8KB half

  // swizzled ds_read fragment offsets (u16 units), constant across slices
  int aoff[AF], boff[4];
#pragma unroll
  for (int m = 0; m < AF; ++m) {
    int row = wr * (AF * 16) + m * 16 + lr;
    int by = row * 64 + lk * 16;
    by ^= ((by >> 9) & 1) << 5;
    aoff[m] = by >> 1;
  }
#pragma unroll
  for (int n = 0; n < 4; ++n) {
    int row = wc * 64 + n * 16 + lr;
    int by = row * 64 + lk * 16;
    by ^= ((by >> 9) & 1) << 5;
    boff[n] = by >> 1;
  }

  const int NS = K >> 5;   // K-slices of 32
  f32x4 acc[AF][4] = {};

#define STG_SLICE(sl) do {                                                                   \
    const size_t kofs = (size_t)(sl) * 32;                                                   \
    u16* Asl = ldsAB + ((sl) & 3) * 8192;                                                    \
    u16* Bsl = ldsAB + 32768 + ((sl) & 3) * BSL;                                             \
    __builtin_amdgcn_global_load_lds(GLBP(A + a0 + kofs), LDSP(Asl + ldsw), 16, 0, 0);       \
    __builtin_amdgcn_global_load_lds(GLBP(A + a1 + kofs), LDSP(Asl + 4096 + ldsw), 16, 0, 0);\
    __builtin_amdgcn_global_load_lds(GLBP(Bt + b0 + kofs), LDSP(Bsl + ldsw), 16, 0, 0);      \
    if (BN == 256)                                                                           \
      __builtin_amdgcn_global_load_lds(GLBP(Bt + b1 + kofs), LDSP(Bsl + 4096 + ldsw), 16, 0, 0); \
  } while (0)

  // prologue: stage slots 0..2 (3 slices in flight), wait for slot 0 only
  STG_SLICE(0);
  STG_SLICE(1);
  STG_SLICE(2);
  if constexpr (BN == 256) asm volatile("s_waitcnt vmcnt(8)" ::: "memory");
  else                     asm volatile("s_waitcnt vmcnt(6)" ::: "memory");
  __builtin_amdgcn_s_barrier();

  for (int s = 0; s < NS; ++s) {
    if (s + 3 < NS) STG_SLICE(s + 3);   // writes slot (s-1)&3: its readers drained last slice
    const u16* As = ldsAB + (s & 3) * 8192;
    const u16* Bs = ldsAB + 32768 + (s & 3) * BSL;
    bf16x8 af[AF], bq[4];
#pragma unroll
    for (int m = 0; m < AF; ++m) af[m] = *(const bf16x8*)(As + aoff[m]);
#pragma unroll
    for (int n = 0; n < 4; ++n) bq[n] = *(const bf16x8*)(Bs + boff[n]);
    asm volatile("s_waitcnt lgkmcnt(0)" ::: "memory");
    __builtin_amdgcn_sched_barrier(0);
    __builtin_amdgcn_s_setprio(1);
#pragma unroll
    for (int n = 0; n < 4; ++n)
#pragma unroll
      for (int m = 0; m < AF; ++m)
        acc[m][n] = __builtin_amdgcn_mfma_f32_16x16x32_bf16(af[m], bq[n], acc[m][n], 0, 0, 0);
    __builtin_amdgcn_s_setprio(0);
    __builtin_amdgcn_sched_barrier(0);
    // counted vmcnt: wait only for the slice-(s+1) slot's loads (issued at s-2)
    const int rem = NS - 1 - s;
    if (rem >= 3) {
      if constexpr (BN == 256) asm volatile("s_waitcnt vmcnt(8)" ::: "memory");
      else                     asm volatile("s_waitcnt vmcnt(6)" ::: "memory");
    } else if (rem == 2) {
      if constexpr (BN == 256) asm volatile("s_waitcnt vmcnt(4)" ::: "memory");
      else                     asm volatile("s_waitcnt vmcnt(3)" ::: "memory");
    } else if (rem == 1) {
      asm volatile("s_waitcnt vmcnt(0)" ::: "memory");
    }
    __builtin_amdgcn_s_barrier();
  }
#undef STG_SLICE

  const int obf = ODYN ? (flags[0] ? 0 : 1) : 0;
#pragma unroll
  for (int m = 0; m < AF; ++m) {
#pragma unroll
    for (int n = 0; n < 4; ++n) {
      const int col = tn + wc * 64 + n * 16 + lr;
      const float bv = bias[col];
#pragma unroll
      for (int j = 0; j < 4; ++j) {
        const int rw = tm + wr * (AF * 16) + m * 16 + lk * 4 + j;
        float vv = acc[m][n][j] + bv;
        if (RES) vv += res[(size_t)rw * N + col];
        if (GELU) vv = geluf(vv);
        if (WF) {
          if (ODYN && obf) ((u16*)outF)[(size_t)rw * N + col] = f2b(vv);
          else ((float*)outF)[(size_t)rw * N + col] = vv;
        }
        if (WB) outB[(size_t)rw * N + col] = f2b(vv);
      }
    }
  }
}

// --------------------------------------------------------------- l2 norms
__global__ __launch_bounds__(256) void l2_q(const float* __restrict__ qpre, u16* __restrict__ Q) {
  const int t = threadIdx.x;
  const int g = blockIdx.x * 64 + (t >> 2);
  const int lg = t & 3;
  const int h = g & (NH_ - 1), sb = g >> 4;
  const float* p = qpre + (size_t)sb * H_ + h * D_ + lg * 32;
  float vv[32];
  float ss = 0.f;
#pragma unroll
  for (int i = 0; i < 8; ++i) {
    float4 a = *(const float4*)&p[i * 4];
    vv[i * 4 + 0] = a.x; vv[i * 4 + 1] = a.y; vv[i * 4 + 2] = a.z; vv[i * 4 + 3] = a.w;
    ss += a.x * a.x + a.y * a.y + a.z * a.z + a.w * a.w;
  }
  ss += __shfl_xor(ss, 1); ss += __shfl_xor(ss, 2);
  const float sc = rsqrtf(ss + 1e-12f);
  const int s = sb >> 1, b = sb & 1;
  u16* o = Q + ((size_t)(b * NH_ + h) * S_ + s) * D_ + lg * 32;
#pragma unroll
  for (int i = 0; i < 4; ++i) {
    bf16x8 ov;
#pragma unroll
    for (int j = 0; j < 8; ++j) ov[j] = (short)f2b(vv[i * 8 + j] * sc);
    *(bf16x8*)&o[i * 8] = ov;
  }
}

__global__ __launch_bounds__(256) void l2_kv(const float* __restrict__ kvpre, u16* __restrict__ Kq, u16* __restrict__ Vt) {
  __shared__ u16 vtT[128][72];
  const int t = threadIdx.x;
  const int bid = blockIdx.x;
  const int mt = bid & 31, h = (bid >> 5) & 15, b = bid >> 9;
  const int lm = t >> 2, lg = t & 3;
  const int m = mt * 64 + lm;
  const size_t rowoff = (size_t)(m * B_ + b) * (2 * H_) + h * 256;
  float vv[32];
  { // K half
    const float* p = kvpre + rowoff + lg * 32;
    float ss = 0.f;
#pragma unroll
    for (int i = 0; i < 8; ++i) {
      float4 a = *(const float4*)&p[i * 4];
      vv[i * 4 + 0] = a.x; vv[i * 4 + 1] = a.y; vv[i * 4 + 2] = a.z; vv[i * 4 + 3] = a.w;
      ss += a.x * a.x + a.y * a.y + a.z * a.z + a.w * a.w;
    }
    ss += __shfl_xor(ss, 1); ss += __shfl_xor(ss, 2);
    const float sc = rsqrtf(ss + 1e-12f);
    u16* o = Kq + ((size_t)(b * NH_ + h) * M_ + m) * D_ + lg * 32;
#pragma unroll
    for (int i = 0; i < 4; ++i) {
      bf16x8 ov;
#pragma unroll
      for (int j = 0; j < 8; ++j) ov[j] = (short)f2b(vv[i * 8 + j] * sc);
      *(bf16x8*)&o[i * 8] = ov;
    }
  }
  { // V half -> LDS transposed
    const float* p = kvpre + rowoff + 128 + lg * 32;
    float ss = 0.f;
#pragma unroll
    for (int i = 0; i < 8; ++i) {
      float4 a = *(const float4*)&p[i * 4];
      vv[i * 4 + 0] = a.x; vv[i * 4 + 1] = a.y; vv[i * 4 + 2] = a.z; vv[i * 4 + 3] = a.w;
      ss += a.x * a.x + a.y * a.y + a.z * a.z + a.w * a.w;
    }
    ss += __shfl_xor(ss, 1); ss += __shfl_xor(ss, 2);
    const float sc = rsqrtf(ss + 1e-12f);
#pragma unroll
    for (int i = 0; i < 32; ++i) vtT[lg * 32 + i][lm] = f2b(vv[i] * sc);
  }
  __syncthreads();
  const int d = t >> 1, half = t & 1;
  u16* o = Vt + ((size_t)(b * NH_ + h) * D_ + d) * M_ + mt * 64 + half * 32;
#pragma unroll
  for (int i = 0; i < 4; ++i) {
    bf16x8 ov = *(const bf16x8*)&vtT[d][half * 32 + i * 8];
    *(bf16x8*)&o[i * 8] = ov;
  }
}

// -------------------------------------------------------------- attention
__global__ __launch_bounds__(256) void attn_k(const u16* __restrict__ Q, const u16* __restrict__ Kq,
                                              const u16* __restrict__ Vt, const u16* __restrict__ MM,
                                              u16* __restrict__ ctx) {
  __shared__ u16 Kl[64 * 128];     // [m][d], source-swizzled
  __shared__ u16 Vl[128 * 64];     // [d][m], source-swizzled
  __shared__ u16 Pl[4][32 * 72];   // per-wave P, padded
  const int t = threadIdx.x, w = t >> 6, l = t & 63, lr = l & 15, lk = l >> 4;
  const int st = blockIdx.x * 128;
  const int bh = blockIdx.y, b = bh >> 4, h = bh & 15;
  const u16* Qb = Q + ((size_t)bh * S_ + st + w * 32) * D_;
  bf16x8 qf[2][4];
#pragma unroll
  for (int sf = 0; sf < 2; ++sf)
#pragma unroll
    for (int kc = 0; kc < 4; ++kc)
      qf[sf][kc] = *(const bf16x8*)&Qb[(sf * 16 + lr) * D_ + kc * 32 + lk * 8];
  f32x4 oacc[2][8] = {};
  float den[2][4] = {};
  const u16* Kb = Kq + (size_t)bh * M_ * D_;
  const u16* Vb = Vt + (size_t)bh * D_ * M_;
  const u16* Mb = MM + (size_t)b * S_ * M_ + (size_t)(st + w * 32) * M_;
  const float invn = 0.08838834764831845f;  // 1/sqrt(128)

  for (int m0 = 0; m0 < M_; m0 += 64) {
#pragma unroll
    for (int i = 0; i < 4; ++i) {
      int j = i * 256 + w * 64 + l;
      int r = j >> 4, c = j & 15, cs = c ^ (r & 7);
      __builtin_amdgcn_global_load_lds(GLBP(Kb + (size_t)(m0 + r) * D_ + cs * 8),
                                       LDSP(&Kl[(i * 256 + w * 64) * 8]), 16, 0, 0);
    }
#pragma unroll
    for (int i = 0; i < 4; ++i) {
      int j = i * 256 + w * 64 + l;
      int r = j >> 3, c = j & 7, cs = c ^ (r & 7);
      __builtin_amdgcn_global_load_lds(GLBP(Vb + (size_t)r * M_ + m0 + cs * 8),
                                       LDSP(&Vl[(i * 256 + w * 64) * 8]), 16, 0, 0);
    }
    __syncthreads();
    f32x4 sc[2][4] = {};
#pragma unroll
    for (int mf = 0; mf < 4; ++mf) {
      int rowm = mf * 16 + lr;
#pragma unroll
      for (int kc = 0; kc < 4; ++kc) {
        int cc = (kc * 4 + lk) ^ (rowm & 7);
        bf16x8 kfv = *(const bf16x8*)&Kl[rowm * 128 + cc * 8];
#pragma unroll
        for (int sf = 0; sf < 2; ++sf)
          sc[sf][mf] = __builtin_amdgcn_mfma_f32_16x16x32_bf16(qf[sf][kc], kfv, sc[sf][mf], 0, 0, 0);
      }
    }
#pragma unroll
    for (int sf = 0; sf < 2; ++sf)
#pragma unroll
      for (int mf = 0; mf < 4; ++mf) {
        int mcol = m0 + mf * 16 + lr;
#pragma unroll
        for (int j2 = 0; j2 < 4; ++j2) {
          int rloc = sf * 16 + lk * 4 + j2;
          float p = __expf(sc[sf][mf][j2] * invn);
          u16 mv = Mb[(size_t)rloc * M_ + mcol];
          p = mv ? p : 0.0f;
          den[sf][j2] += p;
          Pl[w][rloc * 72 + mf * 16 + lr] = f2b(p);
        }
      }
    __syncthreads();
#pragma unroll
    for (int kc2 = 0; kc2 < 2; ++kc2) {
      bf16x8 pa[2];
#pragma unroll
      for (int sf = 0; sf < 2; ++sf)
        pa[sf] = *(const bf16x8*)&Pl[w][(sf * 16 + lr) * 72 + kc2 * 32 + lk * 8];
#pragma unroll
      for (int nf = 0; nf < 8; ++nf) {
        int dd = nf * 16 + lr;
        int cc = (kc2 * 4 + lk) ^ (dd & 7);
        bf16x8 vf = *(const bf16x8*)&Vl[dd * 64 + cc * 8];
#pragma unroll
        for (int sf = 0; sf < 2; ++sf)
          oacc[sf][nf] = __builtin_amdgcn_mfma_f32_16x16x32_bf16(pa[sf], vf, oacc[sf][nf], 0, 0, 0);
      }
    }
    __syncthreads();
  }
#pragma unroll
  for (int sf = 0; sf < 2; ++sf)
#pragma unroll
    for (int j2 = 0; j2 < 4; ++j2) {
      float d = den[sf][j2];
      d += __shfl_xor(d, 1); d += __shfl_xor(d, 2); d += __shfl_xor(d, 4); d += __shfl_xor(d, 8);
      den[sf][j2] = 1.0f / fmaxf(d, 1e-20f);
    }
#pragma unroll
  for (int sf = 0; sf < 2; ++sf)
#pragma unroll
    for (int nf = 0; nf < 8; ++nf)
#pragma unroll
      for (int j2 = 0; j2 < 4; ++j2) {
        int s = st + w * 32 + sf * 16 + lk * 4 + j2;
        int dd = nf * 16 + lr;
        ctx[((size_t)s * B_ + b) * H_ + h * D_ + dd] = f2b(oacc[sf][nf][j2] * den[sf][j2]);
      }
}

// ------------------------------------------------------------------- host
extern "C" void kernel_launch(void* const* d_in, const int* in_sizes, int n_in,
                              void* d_out, int out_size, void* d_ws, size_t ws_size,
                              hipStream_t stream) {
  (void)in_sizes; (void)n_in; (void)out_size; (void)ws_size;
  char* ws = (char*)d_ws;
  u16* WT     = (u16*)(ws + 0);            // 33.55 MB  transposed bf16 weights (reused)
  void* MID   = (void*)(ws + 33554432);    // 67.11 MB  mlp mid bf16 / q_pre f32 / kv_pre f32
  float* XF   = (float*)(ws + 100663296);  // 33.55 MB  running x (f32)
  u16* HB     = (u16*)(ws + 134217728);    // 16.78 MB  LN outputs bf16
  u16* MEMB   = (u16*)(ws + 150994944);    // 16.78 MB  mem bf16, later ctx bf16
  u16* QB     = (u16*)(ws + 167772160);    // 16.78 MB  Q [B][NH][S][D]
  u16* KB     = (u16*)(ws + 184549376);    // 16.78 MB  K [B][NH][M][D]
  u16* VTB    = (u16*)(ws + 201326592);    // 16.78 MB  V^T [B][NH][D][M]
  u16* MMUL   = (u16*)(ws + 218103808);    // 16.78 MB  multiplicative mask bf16
  float* SM   = (float*)(ws + 234881024);  // small f32 arrays
  int* FLAGS  = (int*)(ws + 235044864);

  float* Bias1  = SM + 0;      // b_mlp1_in  8192
  float* Bias1o = SM + 8192;   // b_mlp1_out 2048
  float* BiasQ  = SM + 10240;  // b_q        2048
  float* BiasKV = SM + 12288;  // b_kv       4096
  float* BiasD  = SM + 16384;  // b_dense    2048
  float* Bias2  = SM + 18432;  // b_mlp2_in  8192
  float* Bias2o = SM + 26624;  // b_mlp2_out 2048
  float* G1v = SM + 28672; float* B1v = SM + 30720;
  float* G2v = SM + 32768; float* B2v = SM + 34816;
  float* G3v = SM + 36864; float* B3v = SM + 38912;

  detect_kinds<<<1, 64, 0, stream>>>((const u32*)d_in[0], (const u32*)d_in[2], FLAGS);

  cvt_f32<<<32, 256, 0, stream>>>(d_in[10], FLAGS, Bias1, 8192);
  cvt_f32<<<8, 256, 0, stream>>>(d_in[12], FLAGS, Bias1o, 2048);
  cvt_f32<<<8, 256, 0, stream>>>(d_in[14], FLAGS, BiasQ, 2048);
  cvt_f32<<<16, 256, 0, stream>>>(d_in[16], FLAGS, BiasKV, 4096);
  cvt_f32<<<8, 256, 0, stream>>>(d_in[18], FLAGS, BiasD, 2048);
  cvt_f32<<<32, 256, 0, stream>>>(d_in[20], FLAGS, Bias2, 8192);
  cvt_f32<<<8, 256, 0, stream>>>(d_in[22], FLAGS, Bias2o, 2048);
  cvt_f32<<<8, 256, 0, stream>>>(d_in[3], FLAGS, G1v, 2048);
  cvt_f32<<<8, 256, 0, stream>>>(d_in[4], FLAGS, B1v, 2048);
  cvt_f32<<<8, 256, 0, stream>>>(d_in[5], FLAGS, G2v, 2048);
  cvt_f32<<<8, 256, 0, stream>>>(d_in[6], FLAGS, B2v, 2048);
  cvt_f32<<<8, 256, 0, stream>>>(d_in[7], FLAGS, G3v, 2048);
  cvt_f32<<<8, 256, 0, stream>>>(d_in[8], FLAGS, B3v, 2048);

  mask_cvt<<<(B_ * S_ * M_) / 256, 256, 0, stream>>>(d_in[2], FLAGS, MMUL);
  cast_in_bf16<<<(MB_ * H_ / 8) / 256, 256, 0, stream>>>(d_in[1], FLAGS, MEMB, MB_ * H_ / 8);

  dim3 blk(256);
  dim3 blk5(512);
  // ---- mlp1: x = mlp(ln1(x))  (no residual)
  layernorm_k<1><<<SB_, blk, 0, stream>>>(d_in[0], FLAGS, G1v, B1v, HB);
  transpose_cast<<<dim3(FF_ / 64, H_ / 64), blk, 0, stream>>>(d_in[9], FLAGS, WT, H_, FF_);
  gemm2ph<256, 1, 0, 0, 1, 0><<<dim3(FF_ / 256, SB_ / 256), blk5, 0, stream>>>(HB, WT, Bias1, nullptr, nullptr, (u16*)MID, FLAGS, SB_, FF_, H_);
  transpose_cast<<<dim3(H_ / 64, FF_ / 64), blk, 0, stream>>>(d_in[11], FLAGS, WT, FF_, H_);
  gemm2ph<128, 0, 0, 1, 0, 0><<<dim3(H_ / 128, SB_ / 256), blk5, 0, stream>>>((u16*)MID, WT, Bias1o, nullptr, XF, nullptr, FLAGS, SB_, H_, FF_);

  // ---- memory attention
  layernorm_k<0><<<SB_, blk, 0, stream>>>(XF, FLAGS, G2v, B2v, HB);
  transpose_cast<<<dim3(H_ / 64, H_ / 64), blk, 0, stream>>>(d_in[13], FLAGS, WT, H_, H_);
  gemm2ph<128, 0, 0, 1, 0, 0><<<dim3(H_ / 128, SB_ / 256), blk5, 0, stream>>>(HB, WT, BiasQ, nullptr, MID, nullptr, FLAGS, SB_, H_, H_);
  l2_q<<<(SB_ * NH_) / 64, blk, 0, stream>>>((const float*)MID, QB);
  transpose_cast<<<dim3(2 * H_ / 64, H_ / 64), blk, 0, stream>>>(d_in[15], FLAGS, WT, H_, 2 * H_);
  gemm2ph<256, 0, 0, 1, 0, 0><<<dim3(2 * H_ / 256, MB_ / 256), blk5, 0, stream>>>(MEMB, WT, BiasKV, nullptr, MID, nullptr, FLAGS, MB_, 2 * H_, H_);
  l2_kv<<<B_ * NH_ * (M_ / 64), blk, 0, stream>>>((const float*)MID, KB, VTB);
  attn_k<<<dim3(S_ / 128, B_ * NH_), blk, 0, stream>>>(QB, KB, VTB, MMUL, MEMB);
  transpose_cast<<<dim3(H_ / 64, H_ / 64), blk, 0, stream>>>(d_in[17], FLAGS, WT, H_, H_);
  gemm2ph<128, 0, 1, 1, 0, 0><<<dim3(H_ / 128, SB_ / 256), blk5, 0, stream>>>(MEMB, WT, BiasD, XF, XF, nullptr, FLAGS, SB_, H_, H_);

  // ---- mlp2 with residual
  layernorm_k<0><<<SB_, blk, 0, stream>>>(XF, FLAGS, G3v, B3v, HB);
  transpose_cast<<<dim3(FF_ / 64, H_ / 64), blk, 0, stream>>>(d_in[19], FLAGS, WT, H_, FF_);
  gemm2ph<256, 1, 0, 0, 1, 0><<<dim3(FF_ / 256, SB_ / 256), blk5, 0, stream>>>(HB, WT, Bias2, nullptr, nullptr, (u16*)MID, FLAGS, SB_, FF_, H_);
  transpose_cast<<<dim3(H_ / 64, FF_ / 64), blk, 0, stream>>>(d_in[21], FLAGS, WT, FF_, H_);
  gemm2ph<128, 0, 1, 1, 0, 1><<<dim3(H_ / 128, SB_ / 256), blk5, 0, stream>>>((u16*)MID, WT, Bias2o, XF, d_out, nullptr, FLAGS, SB_, H_, FF_);
}

// Round 4
// 1324.241 us; speedup vs baseline: 1.2314x; 1.0440x over previous
//
#include <hip/hip_runtime.h>
#include <stdint.h>
#include <stddef.h>

typedef __attribute__((ext_vector_type(8))) short bf16x8;
typedef __attribute__((ext_vector_type(4))) float f32x4;
typedef unsigned short u16;
typedef unsigned int u32;

static constexpr int S_ = 2048, B_ = 2, H_ = 2048, NH_ = 16, D_ = 128, M_ = 2048, FF_ = 8192;
static constexpr int SB_ = S_ * B_;   // 4096 rows of x
static constexpr int MB_ = M_ * B_;   // 4096 rows of mem

__device__ __forceinline__ float b2f(u16 b) {
  union { u32 u; float f; } v; v.u = ((u32)b) << 16; return v.f;
}
__device__ __forceinline__ u16 f2b(float f) {
  union { float f; u32 u; } v; v.f = f;
  u32 u = v.u;
  return (u16)((u + 0x7FFFu + ((u >> 16) & 1u)) >> 16);
}
__device__ __forceinline__ float geluf(float x) {
  float x3 = x * x * x;
  return 0.5f * x * (1.0f + tanhf(0.7978845608028654f * (x + 0.044715f * x3)));
}

#define LDSP(p) (reinterpret_cast<__attribute__((address_space(3))) uint32_t*>(reinterpret_cast<uintptr_t>(p)))
#define GLBP(p) (reinterpret_cast<const __attribute__((address_space(1))) uint32_t*>(reinterpret_cast<uintptr_t>(p)))

// ---------------------------------------------------------------- detectors
// flags[0]: 1 = inputs are f32, 0 = inputs are bf16
// flags[1]: mask kind: 0=uint8 bool, 1=int32, 2=bf16, 3=f32
__global__ void detect_kinds(const u32* __restrict__ x0, const u32* __restrict__ mask, int* __restrict__ flags) {
  if (threadIdx.x == 0 && blockIdx.x == 0) {
    int cnt = 0;
    for (int i = 0; i < 256; ++i) {
      u32 e = (x0[i] >> 7) & 0xFFu;   // exponent field if low halfword is a bf16
      if (e >= 118u && e <= 130u) ++cnt;
    }
    flags[0] = (cnt >= 128) ? 0 : 1;
    int all01 = 1, allf = 1, allb = 1;
    for (int i = 0; i < 256; ++i) {
      u32 v = mask[i];
      if (v > 1u) all01 = 0;
      if (v != 0u && v != 0x3F800000u) allf = 0;
      u32 lo = v & 0xFFFFu, hi = v >> 16;
      if ((lo != 0u && lo != 0x3F80u) || (hi != 0u && hi != 0x3F80u)) allb = 0;
    }
    flags[1] = all01 ? 1 : (allf ? 3 : (allb ? 2 : 0));
  }
}

// masked -> 0, unmasked -> bf16(1.0)
__global__ void mask_cvt(const void* __restrict__ mraw, const int* __restrict__ flags, u16* __restrict__ mm) {
  int i = blockIdx.x * 256 + threadIdx.x;
  int kind = flags[1];
  int masked;
  if (kind == 1)      masked = ((const int*)mraw)[i] != 0;
  else if (kind == 3) masked = ((const float*)mraw)[i] != 0.0f;
  else if (kind == 2) masked = ((const u16*)mraw)[i] != 0;
  else                masked = ((const unsigned char*)mraw)[i] != 0;
  mm[i] = masked ? 0 : 0x3F80u;
}

__global__ void cvt_f32(const void* __restrict__ src, const int* __restrict__ flags, float* __restrict__ dst, int n) {
  int i = blockIdx.x * 256 + threadIdx.x;
  if (i < n) dst[i] = flags[0] ? ((const float*)src)[i] : b2f(((const u16*)src)[i]);
}

__global__ void cast_in_bf16(const void* __restrict__ src, const int* __restrict__ flags, u16* __restrict__ dst, int n8) {
  int i = blockIdx.x * 256 + threadIdx.x;
  if (i >= n8) return;
  if (flags[0]) {
    const float4* p = (const float4*)src;
    float4 a = p[i * 2], c = p[i * 2 + 1];
    bf16x8 o;
    o[0] = (short)f2b(a.x); o[1] = (short)f2b(a.y); o[2] = (short)f2b(a.z); o[3] = (short)f2b(a.w);
    o[4] = (short)f2b(c.x); o[5] = (short)f2b(c.y); o[6] = (short)f2b(c.z); o[7] = (short)f2b(c.w);
    *(bf16x8*)&dst[i * 8] = o;
  } else {
    *(bf16x8*)&dst[i * 8] = ((const bf16x8*)src)[i];
  }
}

// ------------------------------------------------------------ transpose+cast
// in [R][C] (f32 or bf16 per flag) -> out [C][R] bf16.  grid (C/64, R/64), 256 thr.
__global__ __launch_bounds__(256) void transpose_cast(const void* __restrict__ in, const int* __restrict__ flags,
                                                      u16* __restrict__ out, int R, int C) {
  __shared__ u16 tile[64][65];
  const int isf = flags[0];
  const int tr = blockIdx.y * 64, tc = blockIdx.x * 64;
  const int tx = threadIdx.x & 63, ty = threadIdx.x >> 6;
  const float* inf = (const float*)in;
  const u16* inb = (const u16*)in;
#pragma unroll
  for (int i = 0; i < 16; ++i) {
    int r = ty * 16 + i;
    size_t idx = (size_t)(tr + r) * C + tc + tx;
    tile[r][tx] = isf ? f2b(inf[idx]) : inb[idx];
  }
  __syncthreads();
#pragma unroll
  for (int i = 0; i < 16; ++i) {
    int c = ty * 16 + i;
    out[(size_t)(tc + c) * R + tr + tx] = tile[tx][c];
  }
}

// ---------------------------------------------------------------- layernorm
template <int EXT>
__global__ __launch_bounds__(256) void layernorm_k(const void* __restrict__ xin, const int* __restrict__ flags,
                                                   const float* __restrict__ g, const float* __restrict__ bta,
                                                   u16* __restrict__ out) {
  const int row = blockIdx.x, t = threadIdx.x;
  float v[8];
  bool bfmode = EXT && (flags[0] == 0);
  if (bfmode) {
    const u16* xr = (const u16*)xin + (size_t)row * H_ + t * 8;
    bf16x8 a = *(const bf16x8*)xr;
#pragma unroll
    for (int j = 0; j < 8; ++j) v[j] = b2f((u16)a[j]);
  } else {
    const float* xr = (const float*)xin + (size_t)row * H_ + t * 8;
    float4 a = *(const float4*)xr, c = *(const float4*)(xr + 4);
    v[0] = a.x; v[1] = a.y; v[2] = a.z; v[3] = a.w;
    v[4] = c.x; v[5] = c.y; v[6] = c.z; v[7] = c.w;
  }
  float s1 = 0.f, s2 = 0.f;
#pragma unroll
  for (int j = 0; j < 8; ++j) { s1 += v[j]; s2 += v[j] * v[j]; }
#pragma unroll
  for (int off = 32; off > 0; off >>= 1) { s1 += __shfl_down(s1, off); s2 += __shfl_down(s2, off); }
  __shared__ float red[8];
  const int w = t >> 6;
  if ((t & 63) == 0) { red[w] = s1; red[4 + w] = s2; }
  __syncthreads();
  s1 = red[0] + red[1] + red[2] + red[3];
  s2 = red[4] + red[5] + red[6] + red[7];
  const float mean = s1 * (1.0f / H_);
  const float rstd = rsqrtf(s2 * (1.0f / H_) - mean * mean + 1e-5f);
  bf16x8 o;
#pragma unroll
  for (int j = 0; j < 8; ++j) {
    float y = (v[j] - mean) * rstd * g[t * 8 + j] + bta[t * 8 + j];
    o[j] = (short)f2b(y);
  }
  *(bf16x8*)(out + (size_t)row * H_ + t * 8) = o;
}

// ------------------------------------------------------------------- GEMM
// BM=256 x BN (256|128), BK=64 slices, 2-slot double buffer, ONE barrier +
// vmcnt(0) per slice.  512 threads = 8 waves.  Rows staged as 128B contiguous
// chunks (DRAM-efficient).  XOR-16B-chunk swizzle (stored = logical ^ (row&7)),
// applied inverse on the global source (rule #21).  2D XCD chunking: each XCD
// gets an 8-wide x (nwg/64)-tall sub-grid -> minimal per-XCD L2 footprint.
template <int BN, int GELU, int RES, int WF, int WB, int ODYN>
__global__ __launch_bounds__(512, 2) void gemm64(const u16* __restrict__ A, const u16* __restrict__ Bt,
                                                 const float* __restrict__ bias, const float* __restrict__ res,
                                                 void* __restrict__ outF, u16* __restrict__ outB,
                                                 const int* __restrict__ flags, int Mr, int N, int K) {
  constexpr int AF = (BN == 256) ? 8 : 4;     // A frags per wave (rows/16)
  constexpr int NB = (BN == 256) ? 4 : 2;     // B loads per thread per slice
  constexpr int BSLOT = BN * 64;              // u16 per B slot
  constexpr int SLOTSTR = 16384 + BSLOT;      // u16 per (A+B) slot pair
  __shared__ u16 lds[2 * SLOTSTR];
  const int t = threadIdx.x;
  const int w = t >> 6, lr = t & 15, lk = (t >> 4) & 3;
  // ---- 2D XCD-chunked block mapping
  const int gx = gridDim.x, gy = gridDim.y;
  const int orig = blockIdx.y * gx + blockIdx.x;
  const int nwg = gx * gy, per = nwg >> 3;
  int tm, tn;
  if ((gx & 7) == 0 && (per & 7) == 0) {
    const int xcd = orig & 7, p = orig >> 3;
    const int ncx = gx >> 3, cy = per >> 3;
    const int ccol = xcd % ncx, crow = xcd / ncx;
    const int px = p & 7, py = p >> 3;
    tn = (ccol * 8 + px) * BN;
    tm = (crow * cy + py) * 256;
  } else {
    tn = (orig % gx) * BN;
    tm = (orig / gx) * 256;
  }
  const int wr = (BN == 256) ? (w >> 2) : (w >> 1);
  const int wc = (BN == 256) ? (w & 3) : (w & 1);

  // ---- staging source addresses (inverse-swizzled 16B chunk within 128B row)
  const int arow = t >> 3;                     // 0..63
  const int aoc = (t & 7) ^ (arow & 7);        // logical chunk for stored chunk (t&7)
  const u16* Asrc = A + (size_t)(tm + arow) * K + aoc * 8;
  const u16* Bsrc = Bt + (size_t)(tn + arow) * K + aoc * 8;
  const int ldsw = w * 512;                    // u16: wave's 1KB chunk in an 8KB issue block

  // ---- ds_read offsets: chunk' = (kk*4+lk) ^ (row&7), row&7 == lr&7
  int ck[2];
#pragma unroll
  for (int kk = 0; kk < 2; ++kk) ck[kk] = ((kk * 4 + lk) ^ (lr & 7)) * 8;
  int arowo[AF], browo[4];
#pragma unroll
  for (int m = 0; m < AF; ++m) arowo[m] = (wr * (AF * 16) + m * 16 + lr) * 64;
#pragma unroll
  for (int n = 0; n < 4; ++n) browo[n] = (wc * 64 + n * 16 + lr) * 64;

  const int NS = K >> 6;   // BK=64 slices
  f32x4 acc[AF][4] = {};

#define STG(sl) do {                                                                              \
    u16* Ad = lds + ((sl) & 1) * SLOTSTR;                                                         \
    u16* Bd = Ad + 16384;                                                                         \
    const size_t ko = (size_t)(sl) * 64;                                                          \
    _Pragma("unroll")                                                                             \
    for (int i = 0; i < 4; ++i)                                                                   \
      __builtin_amdgcn_global_load_lds(GLBP(Asrc + (size_t)(i * 64) * K + ko),                    \
                                       LDSP(Ad + i * 4096 + ldsw), 16, 0, 0);                     \
    _Pragma("unroll")                                                                             \
    for (int i = 0; i < NB; ++i)                                                                  \
      __builtin_amdgcn_global_load_lds(GLBP(Bsrc + (size_t)(i * 64) * K + ko),                    \
                                       LDSP(Bd + i * 4096 + ldsw), 16, 0, 0);                     \
  } while (0)

  STG(0);
  asm volatile("s_waitcnt vmcnt(0)" ::: "memory");
  __builtin_amdgcn_s_barrier();

  for (int s = 0; s < NS; ++s) {
    const bool more = (s + 1 < NS);
    if (more) STG(s + 1);
    const u16* As = lds + (s & 1) * SLOTSTR;
    const u16* Bs = As + 16384;
#pragma unroll
    for (int kk = 0; kk < 2; ++kk) {
      bf16x8 af[AF], bq[4];
#pragma unroll
      for (int m = 0; m < AF; ++m) af[m] = *(const bf16x8*)(As + arowo[m] + ck[kk]);
#pragma unroll
      for (int n = 0; n < 4; ++n) bq[n] = *(const bf16x8*)(Bs + browo[n] + ck[kk]);
      asm volatile("s_waitcnt lgkmcnt(0)" ::: "memory");
      __builtin_amdgcn_sched_barrier(0);
      __builtin_amdgcn_s_setprio(1);
#pragma unroll
      for (int n = 0; n < 4; ++n)
#pragma unroll
        for (int m = 0; m < AF; ++m)
          acc[m][n] = __builtin_amdgcn_mfma_f32_16x16x32_bf16(af[m], bq[n], acc[m][n], 0, 0, 0);
      __builtin_amdgcn_s_setprio(0);
    }
    if (more) {
      asm volatile("s_waitcnt vmcnt(0)" ::: "memory");
      __builtin_amdgcn_s_barrier();
    }
  }
#undef STG

  const int obf = ODYN ? (flags[0] ? 0 : 1) : 0;
#pragma unroll
  for (int m = 0; m < AF; ++m) {
#pragma unroll
    for (int n = 0; n < 4; ++n) {
      const int col = tn + wc * 64 + n * 16 + lr;
      const float bv = bias[col];
#pragma unroll
      for (int j = 0; j < 4; ++j) {
        const int rw = tm + wr * (AF * 16) + m * 16 + lk * 4 + j;
        float vv = acc[m][n][j] + bv;
        if (RES) vv += res[(size_t)rw * N + col];
        if (GELU) vv = geluf(vv);
        if (WF) {
          if (ODYN && obf) ((u16*)outF)[(size_t)rw * N + col] = f2b(vv);
          else ((float*)outF)[(size_t)rw * N + col] = vv;
        }
        if (WB) outB[(size_t)rw * N + col] = f2b(vv);
      }
    }
  }
}

// --------------------------------------------------------------- l2 norms
__global__ __launch_bounds__(256) void l2_q(const float* __restrict__ qpre, u16* __restrict__ Q) {
  const int t = threadIdx.x;
  const int g = blockIdx.x * 64 + (t >> 2);
  const int lg = t & 3;
  const int h = g & (NH_ - 1), sb = g >> 4;
  const float* p = qpre + (size_t)sb * H_ + h * D_ + lg * 32;
  float vv[32];
  float ss = 0.f;
#pragma unroll
  for (int i = 0; i < 8; ++i) {
    float4 a = *(const float4*)&p[i * 4];
    vv[i * 4 + 0] = a.x; vv[i * 4 + 1] = a.y; vv[i * 4 + 2] = a.z; vv[i * 4 + 3] = a.w;
    ss += a.x * a.x + a.y * a.y + a.z * a.z + a.w * a.w;
  }
  ss += __shfl_xor(ss, 1); ss += __shfl_xor(ss, 2);
  const float sc = rsqrtf(ss + 1e-12f);
  const int s = sb >> 1, b = sb & 1;
  u16* o = Q + ((size_t)(b * NH_ + h) * S_ + s) * D_ + lg * 32;
#pragma unroll
  for (int i = 0; i < 4; ++i) {
    bf16x8 ov;
#pragma unroll
    for (int j = 0; j < 8; ++j) ov[j] = (short)f2b(vv[i * 8 + j] * sc);
    *(bf16x8*)&o[i * 8] = ov;
  }
}

__global__ __launch_bounds__(256) void l2_kv(const float* __restrict__ kvpre, u16* __restrict__ Kq, u16* __restrict__ Vt) {
  __shared__ u16 vtT[128][72];
  const int t = threadIdx.x;
  const int bid = blockIdx.x;
  const int mt = bid & 31, h = (bid >> 5) & 15, b = bid >> 9;
  const int lm = t >> 2, lg = t & 3;
  const int m = mt * 64 + lm;
  const size_t rowoff = (size_t)(m * B_ + b) * (2 * H_) + h * 256;
  float vv[32];
  { // K half
    const float* p = kvpre + rowoff + lg * 32;
    float ss = 0.f;
#pragma unroll
    for (int i = 0; i < 8; ++i) {
      float4 a = *(const float4*)&p[i * 4];
      vv[i * 4 + 0] = a.x; vv[i * 4 + 1] = a.y; vv[i * 4 + 2] = a.z; vv[i * 4 + 3] = a.w;
      ss += a.x * a.x + a.y * a.y + a.z * a.z + a.w * a.w;
    }
    ss += __shfl_xor(ss, 1); ss += __shfl_xor(ss, 2);
    const float sc = rsqrtf(ss + 1e-12f);
    u16* o = Kq + ((size_t)(b * NH_ + h) * M_ + m) * D_ + lg * 32;
#pragma unroll
    for (int i = 0; i < 4; ++i) {
      bf16x8 ov;
#pragma unroll
      for (int j = 0; j < 8; ++j) ov[j] = (short)f2b(vv[i * 8 + j] * sc);
      *(bf16x8*)&o[i * 8] = ov;
    }
  }
  { // V half -> LDS transposed
    const float* p = kvpre + rowoff + 128 + lg * 32;
    float ss = 0.f;
#pragma unroll
    for (int i = 0; i < 8; ++i) {
      float4 a = *(const float4*)&p[i * 4];
      vv[i * 4 + 0] = a.x; vv[i * 4 + 1] = a.y; vv[i * 4 + 2] = a.z; vv[i * 4 + 3] = a.w;
      ss += a.x * a.x + a.y * a.y + a.z * a.z + a.w * a.w;
    }
    ss += __shfl_xor(ss, 1); ss += __shfl_xor(ss, 2);
    const float sc = rsqrtf(ss + 1e-12f);
#pragma unroll
    for (int i = 0; i < 32; ++i) vtT[lg * 32 + i][lm] = f2b(vv[i] * sc);
  }
  __syncthreads();
  const int d = t >> 1, half = t & 1;
  u16* o = Vt + ((size_t)(b * NH_ + h) * D_ + d) * M_ + mt * 64 + half * 32;
#pragma unroll
  for (int i = 0; i < 4; ++i) {
    bf16x8 ov = *(const bf16x8*)&vtT[d][half * 32 + i * 8];
    *(bf16x8*)&o[i * 8] = ov;
  }
}

// -------------------------------------------------------------- attention
__global__ __launch_bounds__(256) void attn_k(const u16* __restrict__ Q, const u16* __restrict__ Kq,
                                              const u16* __restrict__ Vt, const u16* __restrict__ MM,
                                              u16* __restrict__ ctx) {
  __shared__ u16 Kl[64 * 128];     // [m][d], source-swizzled
  __shared__ u16 Vl[128 * 64];     // [d][m], source-swizzled
  __shared__ u16 Pl[4][32 * 72];   // per-wave P, padded
  const int t = threadIdx.x, w = t >> 6, l = t & 63, lr = l & 15, lk = l >> 4;
  const int st = blockIdx.x * 128;
  const int bh = blockIdx.y, b = bh >> 4, h = bh & 15;
  const u16* Qb = Q + ((size_t)bh * S_ + st + w * 32) * D_;
  bf16x8 qf[2][4];
#pragma unroll
  for (int sf = 0; sf < 2; ++sf)
#pragma unroll
    for (int kc = 0; kc < 4; ++kc)
      qf[sf][kc] = *(const bf16x8*)&Qb[(sf * 16 + lr) * D_ + kc * 32 + lk * 8];
  f32x4 oacc[2][8] = {};
  float den[2][4] = {};
  const u16* Kb = Kq + (size_t)bh * M_ * D_;
  const u16* Vb = Vt + (size_t)bh * D_ * M_;
  const u16* Mb = MM + (size_t)b * S_ * M_ + (size_t)(st + w * 32) * M_;
  const float invn = 0.08838834764831845f;  // 1/sqrt(128)

  for (int m0 = 0; m0 < M_; m0 += 64) {
#pragma unroll
    for (int i = 0; i < 4; ++i) {
      int j = i * 256 + w * 64 + l;
      int r = j >> 4, c = j & 15, cs = c ^ (r & 7);
      __builtin_amdgcn_global_load_lds(GLBP(Kb + (size_t)(m0 + r) * D_ + cs * 8),
                                       LDSP(&Kl[(i * 256 + w * 64) * 8]), 16, 0, 0);
    }
#pragma unroll
    for (int i = 0; i < 4; ++i) {
      int j = i * 256 + w * 64 + l;
      int r = j >> 3, c = j & 7, cs = c ^ (r & 7);
      __builtin_amdgcn_global_load_lds(GLBP(Vb + (size_t)r * M_ + m0 + cs * 8),
                                       LDSP(&Vl[(i * 256 + w * 64) * 8]), 16, 0, 0);
    }
    __syncthreads();
    f32x4 sc[2][4] = {};
#pragma unroll
    for (int mf = 0; mf < 4; ++mf) {
      int rowm = mf * 16 + lr;
#pragma unroll
      for (int kc = 0; kc < 4; ++kc) {
        int cc = (kc * 4 + lk) ^ (rowm & 7);
        bf16x8 kfv = *(const bf16x8*)&Kl[rowm * 128 + cc * 8];
#pragma unroll
        for (int sf = 0; sf < 2; ++sf)
          sc[sf][mf] = __builtin_amdgcn_mfma_f32_16x16x32_bf16(qf[sf][kc], kfv, sc[sf][mf], 0, 0, 0);
      }
    }
#pragma unroll
    for (int sf = 0; sf < 2; ++sf)
#pragma unroll
      for (int mf = 0; mf < 4; ++mf) {
        int mcol = m0 + mf * 16 + lr;
#pragma unroll
        for (int j2 = 0; j2 < 4; ++j2) {
          int rloc = sf * 16 + lk * 4 + j2;
          float p = __expf(sc[sf][mf][j2] * invn);
          u16 mv = Mb[(size_t)rloc * M_ + mcol];
          p = mv ? p : 0.0f;
          den[sf][j2] += p;
          Pl[w][rloc * 72 + mf * 16 + lr] = f2b(p);
        }
      }
    __syncthreads();
#pragma unroll
    for (int kc2 = 0; kc2 < 2; ++kc2) {
      bf16x8 pa[2];
#pragma unroll
      for (int sf = 0; sf < 2; ++sf)
        pa[sf] = *(const bf16x8*)&Pl[w][(sf * 16 + lr) * 72 + kc2 * 32 + lk * 8];
#pragma unroll
      for (int nf = 0; nf < 8; ++nf) {
        int dd = nf * 16 + lr;
        int cc = (kc2 * 4 + lk) ^ (dd & 7);
        bf16x8 vf = *(const bf16x8*)&Vl[dd * 64 + cc * 8];
#pragma unroll
        for (int sf = 0; sf < 2; ++sf)
          oacc[sf][nf] = __builtin_amdgcn_mfma_f32_16x16x32_bf16(pa[sf], vf, oacc[sf][nf], 0, 0, 0);
      }
    }
    __syncthreads();
  }
#pragma unroll
  for (int sf = 0; sf < 2; ++sf)
#pragma unroll
    for (int j2 = 0; j2 < 4; ++j2) {
      float d = den[sf][j2];
      d += __shfl_xor(d, 1); d += __shfl_xor(d, 2); d += __shfl_xor(d, 4); d += __shfl_xor(d, 8);
      den[sf][j2] = 1.0f / fmaxf(d, 1e-20f);
    }
#pragma unroll
  for (int sf = 0; sf < 2; ++sf)
#pragma unroll
    for (int nf = 0; nf < 8; ++nf)
#pragma unroll
      for (int j2 = 0; j2 < 4; ++j2) {
        int s = st + w * 32 + sf * 16 + lk * 4 + j2;
        int dd = nf * 16 + lr;
        ctx[((size_t)s * B_ + b) * H_ + h * D_ + dd] = f2b(oacc[sf][nf][j2] * den[sf][j2]);
      }
}

// ------------------------------------------------------------------- host
extern "C" void kernel_launch(void* const* d_in, const int* in_sizes, int n_in,
                              void* d_out, int out_size, void* d_ws, size_t ws_size,
                              hipStream_t stream) {
  (void)in_sizes; (void)n_in; (void)out_size; (void)ws_size;
  char* ws = (char*)d_ws;
  u16* WT     = (u16*)(ws + 0);            // 33.55 MB  transposed bf16 weights (reused)
  void* MID   = (void*)(ws + 33554432);    // 67.11 MB  mlp mid bf16 / q_pre f32 / kv_pre f32
  float* XF   = (float*)(ws + 100663296);  // 33.55 MB  running x (f32)
  u16* HB     = (u16*)(ws + 134217728);    // 16.78 MB  LN outputs bf16
  u16* MEMB   = (u16*)(ws + 150994944);    // 16.78 MB  mem bf16, later ctx bf16
  u16* QB     = (u16*)(ws + 167772160);    // 16.78 MB  Q [B][NH][S][D]
  u16* KB     = (u16*)(ws + 184549376);    // 16.78 MB  K [B][NH][M][D]
  u16* VTB    = (u16*)(ws + 201326592);    // 16.78 MB  V^T [B][NH][D][M]
  u16* MMUL   = (u16*)(ws + 218103808);    // 16.78 MB  multiplicative mask bf16
  float* SM   = (float*)(ws + 234881024);  // small f32 arrays
  int* FLAGS  = (int*)(ws + 235044864);

  float* Bias1  = SM + 0;      // b_mlp1_in  8192
  float* Bias1o = SM + 8192;   // b_mlp1_out 2048
  float* BiasQ  = SM + 10240;  // b_q        2048
  float* BiasKV = SM + 12288;  // b_kv       4096
  float* BiasD  = SM + 16384;  // b_dense    2048
  float* Bias2  = SM + 18432;  // b_mlp2_in  8192
  float* Bias2o = SM + 26624;  // b_mlp2_out 2048
  float* G1v = SM + 28672; float* B1v = SM + 30720;
  float* G2v = SM + 32768; float* B2v = SM + 34816;
  float* G3v = SM + 36864; float* B3v = SM + 38912;

  detect_kinds<<<1, 64, 0, stream>>>((const u32*)d_in[0], (const u32*)d_in[2], FLAGS);

  cvt_f32<<<32, 256, 0, stream>>>(d_in[10], FLAGS, Bias1, 8192);
  cvt_f32<<<8, 256, 0, stream>>>(d_in[12], FLAGS, Bias1o, 2048);
  cvt_f32<<<8, 256, 0, stream>>>(d_in[14], FLAGS, BiasQ, 2048);
  cvt_f32<<<16, 256, 0, stream>>>(d_in[16], FLAGS, BiasKV, 4096);
  cvt_f32<<<8, 256, 0, stream>>>(d_in[18], FLAGS, BiasD, 2048);
  cvt_f32<<<32, 256, 0, stream>>>(d_in[20], FLAGS, Bias2, 8192);
  cvt_f32<<<8, 256, 0, stream>>>(d_in[22], FLAGS, Bias2o, 2048);
  cvt_f32<<<8, 256, 0, stream>>>(d_in[3], FLAGS, G1v, 2048);
  cvt_f32<<<8, 256, 0, stream>>>(d_in[4], FLAGS, B1v, 2048);
  cvt_f32<<<8, 256, 0, stream>>>(d_in[5], FLAGS, G2v, 2048);
  cvt_f32<<<8, 256, 0, stream>>>(d_in[6], FLAGS, B2v, 2048);
  cvt_f32<<<8, 256, 0, stream>>>(d_in[7], FLAGS, G3v, 2048);
  cvt_f32<<<8, 256, 0, stream>>>(d_in[8], FLAGS, B3v, 2048);

  mask_cvt<<<(B_ * S_ * M_) / 256, 256, 0, stream>>>(d_in[2], FLAGS, MMUL);
  cast_in_bf16<<<(MB_ * H_ / 8) / 256, 256, 0, stream>>>(d_in[1], FLAGS, MEMB, MB_ * H_ / 8);

  dim3 blk(256);
  dim3 blk5(512);
  // ---- mlp1: x = mlp(ln1(x))  (no residual)
  layernorm_k<1><<<SB_, blk, 0, stream>>>(d_in[0], FLAGS, G1v, B1v, HB);
  transpose_cast<<<dim3(FF_ / 64, H_ / 64), blk, 0, stream>>>(d_in[9], FLAGS, WT, H_, FF_);
  gemm64<256, 1, 0, 0, 1, 0><<<dim3(FF_ / 256, SB_ / 256), blk5, 0, stream>>>(HB, WT, Bias1, nullptr, nullptr, (u16*)MID, FLAGS, SB_, FF_, H_);
  transpose_cast<<<dim3(H_ / 64, FF_ / 64), blk, 0, stream>>>(d_in[11], FLAGS, WT, FF_, H_);
  gemm64<128, 0, 0, 1, 0, 0><<<dim3(H_ / 128, SB_ / 256), blk5, 0, stream>>>((u16*)MID, WT, Bias1o, nullptr, XF, nullptr, FLAGS, SB_, H_, FF_);

  // ---- memory attention
  layernorm_k<0><<<SB_, blk, 0, stream>>>(XF, FLAGS, G2v, B2v, HB);
  transpose_cast<<<dim3(H_ / 64, H_ / 64), blk, 0, stream>>>(d_in[13], FLAGS, WT, H_, H_);
  gemm64<128, 0, 0, 1, 0, 0><<<dim3(H_ / 128, SB_ / 256), blk5, 0, stream>>>(HB, WT, BiasQ, nullptr, MID, nullptr, FLAGS, SB_, H_, H_);
  l2_q<<<(SB_ * NH_) / 64, blk, 0, stream>>>((const float*)MID, QB);
  transpose_cast<<<dim3(2 * H_ / 64, H_ / 64), blk, 0, stream>>>(d_in[15], FLAGS, WT, H_, 2 * H_);
  gemm64<256, 0, 0, 1, 0, 0><<<dim3(2 * H_ / 256, MB_ / 256), blk5, 0, stream>>>(MEMB, WT, BiasKV, nullptr, MID, nullptr, FLAGS, MB_, 2 * H_, H_);
  l2_kv<<<B_ * NH_ * (M_ / 64), blk, 0, stream>>>((const float*)MID, KB, VTB);
  attn_k<<<dim3(S_ / 128, B_ * NH_), blk, 0, stream>>>(QB, KB, VTB, MMUL, MEMB);
  transpose_cast<<<dim3(H_ / 64, H_ / 64), blk, 0, stream>>>(d_in[17], FLAGS, WT, H_, H_);
  gemm64<128, 0, 1, 1, 0, 0><<<dim3(H_ / 128, SB_ / 256), blk5, 0, stream>>>(MEMB, WT, BiasD, XF, XF, nullptr, FLAGS, SB_, H_, H_);

  // ---- mlp2 with residual
  layernorm_k<0><<<SB_, blk, 0, stream>>>(XF, FLAGS, G3v, B3v, HB);
  transpose_cast<<<dim3(FF_ / 64, H_ / 64), blk, 0, stream>>>(d_in[19], FLAGS, WT, H_, FF_);
  gemm64<256, 1, 0, 0, 1, 0><<<dim3(FF_ / 256, SB_ / 256), blk5, 0, stream>>>(HB, WT, Bias2, nullptr, nullptr, (u16*)MID, FLAGS, SB_, FF_, H_);
  transpose_cast<<<dim3(H_ / 64, FF_ / 64), blk, 0, stream>>>(d_in[21], FLAGS, WT, FF_, H_);
  gemm64<128, 0, 1, 1, 0, 1><<<dim3(H_ / 128, SB_ / 256), blk5, 0, stream>>>((u16*)MID, WT, Bias2o, XF, d_out, nullptr, FLAGS, SB_, H_, FF_);
}